// Round 5
// baseline (967.553 us; speedup 1.0000x reference)
//
#include <hip/hip_runtime.h>
#include <type_traits>
#include <cstdint>
#include <cstddef>

#define N_FEAT 32
#define NBASIS 8

// ---------------------------------------------------------------------------
// Compile-time Clebsch-Gordan (real basis) table: constexpr port of the
// reference _cg / _u_real / _real_cg.  Values become inline literals in the
// unrolled MP kernels; zero entries are eliminated via `if constexpr`.
// ---------------------------------------------------------------------------
namespace cgc {

constexpr double dfact(int n){ double r=1.0; for(int i=2;i<=n;++i) r*=(double)i; return r; }

constexpr double dsqrt(double x){
  if(x<=0.0) return 0.0;
  double g = x>1.0 ? x : 1.0;
  for(int i=0;i<200;++i){ double ng = 0.5*(g + x/g); if(ng==g) break; g=ng; }
  return g;
}

constexpr double cg1(int j1,int m1,int j2,int m2,int j3,int m3){
  int adiff = j1-j2; if(adiff<0) adiff=-adiff;
  if(m1+m2!=m3 || j3<adiff || j3>j1+j2) return 0.0;
  double pre = dsqrt((double)(2*j3+1)*dfact(j1+j2-j3)*dfact(j1-j2+j3)*dfact(-j1+j2+j3)/dfact(j1+j2+j3+1));
  pre = pre*dsqrt(dfact(j3+m3)*dfact(j3-m3)*dfact(j1-m1)*dfact(j1+m1)*dfact(j2-m2)*dfact(j2+m2));
  double s=0.0;
  for(int k=0;k<=j1+j2+j3;++k){
    int d1=j1+j2-j3-k, d2=j1-m1-k, d3=j2+m2-k, d4=j3-j2+m1+k, d5=j3-j1-m2+k;
    if(d1<0||d2<0||d3<0||d4<0||d5<0) continue;
    double term = 1.0/(dfact(k)*dfact(d1)*dfact(d2)*dfact(d3)*dfact(d4)*dfact(d5));
    s += (k&1)? -term : term;
  }
  return pre*s;
}

struct Tab { float v[9][9][9]; };

constexpr Tab make(){
  Tab T{};
  int off[3]={0,1,4};
  double Ure[3][5][5]={}, Uim[3][5][5]={};
  const double s2 = dsqrt(0.5);
  for(int l=0;l<3;++l){
    for(int m=-l;m<=l;++m){
      int i=m+l;
      if(m==0){ Ure[l][i][l]=1.0; }
      else if(m>0){
        Ure[l][i][l+m] = ((m&1)? -1.0:1.0)*s2;
        Ure[l][i][l-m] = s2;
      } else {
        int am=-m;
        Uim[l][i][l+m] = s2;
        Uim[l][i][l-m] = -(((am&1)?-1.0:1.0))*s2;
      }
    }
  }
  for(int l1=0;l1<3;++l1) for(int l2=0;l2<3;++l2) for(int l3=0;l3<3;++l3){
    int lo = l1-l2; if(lo<0) lo=-lo;
    if(l3<lo || l3>l1+l2) continue;
    int d1=2*l1+1, d2=2*l2+1, d3=2*l3+1;
    double cg[5][5][5]={};
    for(int m1=-l1;m1<=l1;++m1) for(int m2=-l2;m2<=l2;++m2){
      int m3=m1+m2;
      if(m3>=-l3 && m3<=l3) cg[m1+l1][m2+l2][m3+l3] = cg1(l1,m1,l2,m2,l3,m3);
    }
    double t1re[5][5][5]={}, t1im[5][5][5]={};
    for(int a=0;a<d1;++a) for(int b=0;b<d2;++b) for(int k=0;k<d3;++k){
      double sre=0, sim=0;
      for(int c=0;c<d3;++c){
        double g=cg[a][b][c]; if(g==0.0) continue;
        sre += g*Ure[l3][k][c];
        sim -= g*Uim[l3][k][c];
      }
      t1re[a][b][k]=sre; t1im[a][b][k]=sim;
    }
    double t2re[5][5][5]={}, t2im[5][5][5]={};
    for(int a=0;a<d1;++a) for(int j=0;j<d2;++j) for(int k=0;k<d3;++k){
      double sre=0,sim=0;
      for(int b=0;b<d2;++b){
        double ur=Ure[l2][j][b], ui=Uim[l2][j][b];
        if(ur==0.0&&ui==0.0) continue;
        sre += ur*t1re[a][b][k]-ui*t1im[a][b][k];
        sim += ur*t1im[a][b][k]+ui*t1re[a][b][k];
      }
      t2re[a][j][k]=sre; t2im[a][j][k]=sim;
    }
    for(int i=0;i<d1;++i) for(int j=0;j<d2;++j) for(int k=0;k<d3;++k){
      double sre=0,sim=0;
      for(int a=0;a<d1;++a){
        double ur=Ure[l1][i][a], ui=Uim[l1][i][a];
        if(ur==0.0&&ui==0.0) continue;
        sre += ur*t2re[a][j][k]-ui*t2im[a][j][k];
        sim += ur*t2im[a][j][k]+ui*t2re[a][j][k];
      }
      T.v[off[l1]+i][off[l2]+j][off[l3]+k] = (float)(sre+sim);
    }
  }
  return T;
}

constexpr Tab T = make();

} // namespace cgc

template<int I, int N, typename F>
__device__ __forceinline__ void sfor(F&& f){
  if constexpr (I < N){
    f(std::integral_constant<int,I>{});
    sfor<I+1,N>(static_cast<F&&>(f));
  }
}

constexpr int LOFF[3] = {0,1,4};

// Path sets.  Layer-1's 15 paths split by l1 so Wreg fits in registers
// without spilling (R3/R4 post-mortem).
struct PS0 {   // layer 0
  static constexpr int NP=3;
  static constexpr int L[3][3]={{0,0,0},{0,1,1},{0,2,2}};
  static constexpr int ALO=0, AHI=1, OD=9, WOFF=0;
  static constexpr bool ACC=false;
};
struct PS1a {  // layer 1, l1 in {0,1}
  static constexpr int NP=9;
  static constexpr int L[9][3]={{0,0,0},{0,1,1},{0,2,2},
                                {1,0,1},{1,1,0},{1,1,1},{1,1,2},{1,2,1},{1,2,2}};
  static constexpr int ALO=0, AHI=4, OD=9, WOFF=0;
  static constexpr bool ACC=false;
};
struct PS1b {  // layer 1, l1 == 2 (W rows 9..14), accumulates into y_out
  static constexpr int NP=6;
  static constexpr int L[6][3]={{2,0,2},{2,1,1},{2,1,2},{2,2,0},{2,2,1},{2,2,2}};
  static constexpr int ALO=4, AHI=9, OD=9, WOFF=9*NBASIS*N_FEAT;
  static constexpr bool ACC=true;
};
struct PS2 {   // layer 2
  static constexpr int NP=3;
  static constexpr int L[3][3]={{0,0,0},{1,1,0},{2,2,0}};
  static constexpr int ALO=0, AHI=9, OD=1, WOFF=0;
  static constexpr bool ACC=false;
};

// ---------------------------------------------------------------------------
// CSR construction on dst (idx_i). perm[e] = CSR slot of original edge e.
// ---------------------------------------------------------------------------
__global__ void zero_kernel(int* __restrict__ a, int n){
  int i = blockIdx.x*256 + threadIdx.x;
  if(i<n) a[i]=0;
}

__global__ void count_kernel(const int* __restrict__ dst, int* __restrict__ cnt, int E){
  int e = blockIdx.x*256 + threadIdx.x;
  if(e<E) atomicAdd(&cnt[dst[e]], 1);
}

__global__ void __launch_bounds__(1024) scan_kernel(const int* __restrict__ cnt,
                                                    int* __restrict__ row_ptr,
                                                    int* __restrict__ cursor, int n){
  __shared__ int part[1024];
  const int tid = threadIdx.x;
  const int chunk = (n + 1023) >> 10;
  const int s0 = tid*chunk;
  const int s1 = (s0+chunk < n) ? s0+chunk : n;
  int s=0;
  for(int i=s0;i<s1;++i) s += cnt[i];
  part[tid]=s; __syncthreads();
  for(int off=1; off<1024; off<<=1){
    int v = 0;
    if(tid>=off) v = part[tid-off];
    __syncthreads();
    part[tid] += v;
    __syncthreads();
  }
  int run = part[tid] - s;           // exclusive prefix
  for(int i=s0;i<s1;++i){
    int cv = cnt[i];
    row_ptr[i]=run; cursor[i]=run;
    run += cv;
  }
  if(tid==1023) row_ptr[n] = part[1023];
}

__global__ void fill_kernel(const int* __restrict__ dst, const int* __restrict__ src,
                            int* __restrict__ cursor, int* __restrict__ perm,
                            int* __restrict__ srcs, int E){
  int e = blockIdx.x*256 + threadIdx.x;
  if(e<E){
    int d = dst[e];
    int pos = atomicAdd(&cursor[d], 1);
    perm[e] = pos;
    srcs[pos] = src[e];
  }
}

// ---------------------------------------------------------------------------
// Per-edge geometry, written PERMUTED into CSR order (stride 20 floats):
// rad[8] (cutoff*mask folded) + Y[9] + 3 pad.
// ---------------------------------------------------------------------------
__global__ void geom_kernel(const float* __restrict__ dr, const int* __restrict__ ii,
                            const int* __restrict__ jj, const int* __restrict__ perm,
                            float* __restrict__ radY, int E){
  int e = blockIdx.x*256 + threadIdx.x;
  if(e>=E) return;
  float dx=dr[3*e], dy=dr[3*e+1], dz=dr[3*e+2];
  float r2 = fmaf(dx,dx,fmaf(dy,dy,fmaf(dz,dz,1e-12f)));
  float r = sqrtf(r2);
  float inv = 1.f/r;
  float ux=dx*inv, uy=dy*inv, uz=dz*inv;
  float t = r*(1.f/6.f);
  t = fminf(fmaxf(t,0.f), 1.f-1e-6f);
  float cut = 0.f;
  if (r < 6.f) cut = expf(1.f - 1.f/(1.f - t*t));
  if (ii[e]==jj[e]) cut = 0.f;
  float base = 0.57735026918962576f * inv * cut;   // sqrt(2/RMAX)=sqrt(1/3)
  float* o = radY + (size_t)perm[e]*20;
  const float pir = 0.52359877559829887f * r;      // pi*r/6
  #pragma unroll
  for(int nb=1; nb<=8; ++nb) o[nb-1] = base * sinf((float)nb * pir);
  o[8]  = 0.28209479177387814f;
  o[9]  = 0.4886025119029199f*uy;
  o[10] = 0.4886025119029199f*uz;
  o[11] = 0.4886025119029199f*ux;
  o[12] = 1.0925484305920792f*ux*uy;
  o[13] = 1.0925484305920792f*uy*uz;
  o[14] = 0.31539156525252005f*(3.f*uz*uz-1.f);
  o[15] = 1.0925484305920792f*ux*uz;
  o[16] = 0.5462742152960396f*(ux*ux-uy*uy);
  o[17]=0.f; o[18]=0.f; o[19]=0.f;
}

__global__ void init_kernel(const float* __restrict__ embed, const int* __restrict__ Z,
                            float* __restrict__ xA, int nN){
  int i = blockIdx.x*256 + threadIdx.x;
  if(i >= nN*N_FEAT) return;
  int n = i>>5, f = i&31;
  xA[(size_t)n*288 + f] = embed[Z[n]*N_FEAT + f];
}

// ---------------------------------------------------------------------------
// Message passing.  Grid-stride over nodes: each block loads its path
// weights ONCE, then sequentially owns many dst nodes (R4 post-mortem: the
// per-node W prologue (72 loads/thread) was ~as large as the ~4-iteration
// edge loop it fed).  Per node: 8 interleaved edge streams (4 waves x 2
// halves), lane = feature; 1-deep register prefetch of radY + x[src];
// 2-deep of srcs; LDS tree-reduce across waves; write (or += for PS1b).
// ---------------------------------------------------------------------------
#define MP_GRID 1024

template<class PS>
__global__ void __launch_bounds__(256, 4) mp_kernel(
    const int* __restrict__ row_ptr, const int* __restrict__ srcs,
    const float* __restrict__ radY, const float* __restrict__ x_in,
    const float* __restrict__ W, float* __restrict__ y_out, int nN)
{
  constexpr int NP = PS::NP;
  constexpr int ALO = PS::ALO, AHI = PS::AHI, DA = AHI-ALO;
  constexpr int OD = PS::OD;
  const int tid  = threadIdx.x;
  const int f    = tid & 31;
  const int t    = tid >> 5;        // stream 0..7
  const int wave = tid >> 6;
  const bool lo32 = (tid & 63) < 32;

  __shared__ float red[3][OD][32];

  // path weights resident in VGPRs: lane f holds W[p][q][f] — loaded once
  float Wreg[NP][NBASIS];
  sfor<0,NP>([&](auto P){
    sfor<0,NBASIS>([&](auto Q){
      Wreg[P.value][Q.value] = W[PS::WOFF + (P.value*NBASIS+Q.value)*N_FEAT + f];
    });
  });

  for (int n = blockIdx.x; n < nN; n += MP_GRID){
    float msg[OD];
    sfor<0,OD>([&](auto C){ msg[C.value]=0.f; });

    const int beg = row_ptr[n], end = row_ptr[n+1];

    int k = beg + t;
    int srcB = 0;
    float4 rA0, rA1, rA2, rA3; float yA8;
    float xsA[DA];
    if (k < end){
      const float* rp = radY + (size_t)k*20;
      rA0 = *(const float4*)(rp);
      rA1 = *(const float4*)(rp+4);
      rA2 = *(const float4*)(rp+8);
      rA3 = *(const float4*)(rp+12);
      yA8 = rp[16];
      int srcA = srcs[k];
      if (k+8 < end) srcB = srcs[k+8];
      const float* xb = x_in + (size_t)srcA*288 + ALO*N_FEAT + f;
      sfor<0,DA>([&](auto A){ xsA[A.value] = xb[A.value*N_FEAT]; });
    }

    for (; k < end; ){
      const int kn = k + 8;
      // prefetch next edge: radY + x[src] in flight across this compute
      float4 rB0, rB1, rB2, rB3; float yB8;
      float xsB[DA]; int srcC = 0;
      if (kn < end){
        const float* rp = radY + (size_t)kn*20;
        rB0 = *(const float4*)(rp);
        rB1 = *(const float4*)(rp+4);
        rB2 = *(const float4*)(rp+8);
        rB3 = *(const float4*)(rp+12);
        yB8 = rp[16];
        const float* xb = x_in + (size_t)srcB*288 + ALO*N_FEAT + f;
        sfor<0,DA>([&](auto A){ xsB[A.value] = xb[A.value*N_FEAT]; });
        if (kn+8 < end) srcC = srcs[kn+8];
      }

      const float rad[8] = {rA0.x,rA0.y,rA0.z,rA0.w,rA1.x,rA1.y,rA1.z,rA1.w};
      const float Yv[9]  = {rA2.x,rA2.y,rA2.z,rA2.w,rA3.x,rA3.y,rA3.z,rA3.w,yA8};

      sfor<0,NP>([&](auto P){
        constexpr int p  = P.value;
        constexpr int l1 = PS::L[p][0], l2 = PS::L[p][1], l3 = PS::L[p][2];
        constexpr int o1 = LOFF[l1], o2 = LOFF[l2], o3 = LOFF[l3];
        float w = 0.f;
        sfor<0,NBASIS>([&](auto Q){ w = fmaf(rad[Q.value], Wreg[p][Q.value], w); });
        sfor<0,2*l2+1>([&](auto B){
          constexpr int b = B.value;
          const float yw = Yv[o2+b]*w;
          sfor<0,2*l1+1>([&](auto A){
            constexpr int a = A.value;
            sfor<0,2*l3+1>([&](auto C){
              constexpr int c = C.value;
              constexpr float cgv = cgc::T.v[o1+a][o2+b][o3+c];
              if constexpr (cgv > 1e-7f || cgv < -1e-7f){
                msg[o3+c] = fmaf(cgv*xsA[o1+a-ALO], yw, msg[o3+c]);
              }
            });
          });
        });
      });

      // rotate pipeline
      rA0=rB0; rA1=rB1; rA2=rB2; rA3=rB3; yA8=yB8;
      sfor<0,DA>([&](auto A){ xsA[A.value] = xsB[A.value]; });
      srcB = srcC;
      k = kn;
    }

    // merge half-waves within each wave
    sfor<0,OD>([&](auto C){ msg[C.value] += __shfl_down(msg[C.value], 32, 64); });

    if (wave > 0 && lo32){
      sfor<0,OD>([&](auto C){ red[wave-1][C.value][f] = msg[C.value]; });
    }
    __syncthreads();
    if (wave == 0 && lo32){
      sfor<0,OD>([&](auto C){
        float v = msg[C.value] + red[0][C.value][f] + red[1][C.value][f] + red[2][C.value][f];
        if constexpr (PS::ACC)
          y_out[((size_t)n*OD + C.value)*N_FEAT + f] += v;
        else
          y_out[((size_t)n*OD + C.value)*N_FEAT + f] = v;
      });
    }
    __syncthreads();   // red safe for next node
  }
}

// ---------------------------------------------------------------------------
// Node update for iterations 0/1: x_out = eadd(x, dense2(esilu(dense1(eadd(x,msg)))))
// ---------------------------------------------------------------------------
template<int DX>
__global__ void __launch_bounds__(256) nodeA_kernel(
    const float* __restrict__ xin, const float* __restrict__ ymsg,
    const float* __restrict__ K1, const float* __restrict__ b1,
    const float* __restrict__ K2, const float* __restrict__ b2,
    float* __restrict__ xout, int nN)
{
  __shared__ float sK1[1024], sK2[1024], sb1[32], sb2[32];
  __shared__ float tb[8][9][32];
  const int tid = threadIdx.x;
  for(int i=tid;i<1024;i+=256){ sK1[i]=K1[i]; sK2[i]=K2[i]; }
  if(tid<32){ sb1[tid]=b1[tid]; sb2[tid]=b2[tid]; }
  __syncthreads();
  const int h = tid>>5, f = tid&31;
  const int n = blockIdx.x*8 + h;
  const bool valid = n < nN;
  const int nc = valid ? n : 0;
  float xi[9];
  #pragma unroll
  for(int c=0;c<9;++c){
    float t = ymsg[((size_t)nc*9+c)*32+f];
    float x = 0.f;
    if (c<DX) x = xin[((size_t)nc*9+c)*32+f];
    xi[c]=x;
    tb[h][c][f] = t + x;
  }
  __syncthreads();
  float u[9];
  #pragma unroll
  for(int c=0;c<9;++c){
    float acc = (c==0) ? sb1[f] : 0.f;
    #pragma unroll
    for(int g=0;g<32;++g) acc = fmaf(tb[h][c][g], sK1[g*32+f], acc);
    u[c]=acc;
  }
  const float gate = 1.f/(1.f+expf(-u[0]));   // silu(s)=s*gate; others *gate
  __syncthreads();
  #pragma unroll
  for(int c=0;c<9;++c) tb[h][c][f] = u[c]*gate;
  __syncthreads();
  #pragma unroll
  for(int c=0;c<9;++c){
    float acc = (c==0) ? sb2[f] : 0.f;
    #pragma unroll
    for(int g=0;g<32;++g) acc = fmaf(tb[h][c][g], sK2[g*32+f], acc);
    if (valid) xout[((size_t)n*9+c)*32+f] = acc + ((c<DX) ? xi[c] : 0.f);
  }
}

// Final iteration node update: scalar channel only; writes d_out (nN,32)
__global__ void __launch_bounds__(256) nodeB_kernel(
    const float* __restrict__ xin, const float* __restrict__ msg0,
    const float* __restrict__ K1, const float* __restrict__ b1,
    const float* __restrict__ K2, const float* __restrict__ b2,
    float* __restrict__ out, int nN)
{
  __shared__ float sK1[1024], sK2[1024], sb1[32], sb2[32];
  __shared__ float tb[8][32];
  const int tid = threadIdx.x;
  for(int i=tid;i<1024;i+=256){ sK1[i]=K1[i]; sK2[i]=K2[i]; }
  if(tid<32){ sb1[tid]=b1[tid]; sb2[tid]=b2[tid]; }
  __syncthreads();
  const int h = tid>>5, f = tid&31;
  const int n = blockIdx.x*8 + h;
  const bool valid = n < nN;
  const int nc = valid ? n : 0;
  const float x0 = xin[(size_t)nc*288 + f];      // x[:, 0:1] scalar channel
  tb[h][f] = msg0[(size_t)nc*32+f] + x0;
  __syncthreads();
  float acc = sb1[f];
  #pragma unroll
  for(int g=0;g<32;++g) acc = fmaf(tb[h][g], sK1[g*32+f], acc);
  const float gate = 1.f/(1.f+expf(-acc));
  const float v = acc*gate;
  __syncthreads();
  tb[h][f] = v;
  __syncthreads();
  float acc2 = sb2[f];
  #pragma unroll
  for(int g=0;g<32;++g) acc2 = fmaf(tb[h][g], sK2[g*32+f], acc2);
  if (valid) out[(size_t)n*32+f] = x0 + acc2;
}

// ---------------------------------------------------------------------------
extern "C" void kernel_launch(void* const* d_in, const int* in_sizes, int n_in,
                              void* d_out, int out_size, void* d_ws, size_t ws_size,
                              hipStream_t stream) {
  const float* dr    = (const float*)d_in[0];
  const int*   Z     = (const int*)  d_in[1];
  const int*   nbr   = (const int*)  d_in[2];
  const float* embed = (const float*)d_in[3];
  const float* wmp0  = (const float*)d_in[4];
  const float* wmp1  = (const float*)d_in[5];
  const float* wmp2  = (const float*)d_in[6];
  const float* dk1   = (const float*)d_in[7];
  const float* db1   = (const float*)d_in[8];
  const float* dk2   = (const float*)d_in[9];
  const float* db2   = (const float*)d_in[10];
  const int nN = in_sizes[1];
  const int E  = in_sizes[2]/2;
  const int* idx_i = nbr;       // dst
  const int* idx_j = nbr + E;   // src

  // workspace carve-up (256B aligned)
  uintptr_t base = (uintptr_t)d_ws;
  auto alloc = [&](size_t bytes)->void*{
    uintptr_t p = (base + 255) & ~(uintptr_t)255;
    base = p + bytes;
    return (void*)p;
  };
  float* radY    = (float*)alloc((size_t)E*20*4);
  int*   cnt     = (int*)  alloc((size_t)nN*4);
  int*   cursor  = (int*)  alloc((size_t)nN*4);
  int*   row_ptr = (int*)  alloc((size_t)(nN+1)*4);
  int*   perm    = (int*)  alloc((size_t)E*4);
  int*   srcs    = (int*)  alloc((size_t)E*4);
  float* xA      = (float*)alloc((size_t)nN*288*4);
  float* xB      = (float*)alloc((size_t)nN*288*4);
  float* ymsg    = (float*)alloc((size_t)nN*288*4);

  const int gE = (E+255)/256;
  const int gN = (nN+255)/256;

  // CSR build on dst
  zero_kernel <<<gN, 256, 0, stream>>>(cnt, nN);
  count_kernel<<<gE, 256, 0, stream>>>(idx_i, cnt, E);
  scan_kernel <<<1, 1024, 0, stream>>>(cnt, row_ptr, cursor, nN);
  fill_kernel <<<gE, 256, 0, stream>>>(idx_i, idx_j, cursor, perm, srcs, E);

  // edge geometry (scattered into CSR order) + node embedding
  geom_kernel <<<gE, 256, 0, stream>>>(dr, idx_i, idx_j, perm, radY, E);
  init_kernel <<<(nN*N_FEAT+255)/256, 256, 0, stream>>>(embed, Z, xA, nN);

  const int gND = (nN+7)/8;     // 8 nodes (half-waves) per block
  const int gMP = (nN < MP_GRID) ? nN : MP_GRID;

  // iteration 0
  mp_kernel<PS0><<<gMP, 256, 0, stream>>>(row_ptr, srcs, radY, xA, wmp0, ymsg, nN);
  nodeA_kernel<1><<<gND, 256, 0, stream>>>(xA, ymsg, dk1, db1, dk2, db2, xB, nN);
  // iteration 1 (two passes: l1 in {0,1}, then l1==2 accumulating)
  mp_kernel<PS1a><<<gMP, 256, 0, stream>>>(row_ptr, srcs, radY, xB, wmp1, ymsg, nN);
  mp_kernel<PS1b><<<gMP, 256, 0, stream>>>(row_ptr, srcs, radY, xB, wmp1, ymsg, nN);
  nodeA_kernel<9><<<gND, 256, 0, stream>>>(xB, ymsg, dk1+1024, db1+32, dk2+1024, db2+32, xA, nN);
  // iteration 2 (scalar output)
  mp_kernel<PS2><<<gMP, 256, 0, stream>>>(row_ptr, srcs, radY, xA, wmp2, ymsg, nN);
  nodeB_kernel<<<gND, 256, 0, stream>>>(xA, ymsg, dk1+2048, db1+64, dk2+2048, db2+64,
                                        (float*)d_out, nN);
}

// Round 6
// 604.993 us; speedup vs baseline: 1.5993x; 1.5993x over previous
//
#include <hip/hip_runtime.h>
#include <type_traits>
#include <cstdint>
#include <cstddef>

#define N_FEAT 32
#define NBASIS 8

// ---------------------------------------------------------------------------
// Compile-time Clebsch-Gordan (real basis) table: constexpr port of the
// reference _cg / _u_real / _real_cg.  Values become inline literals in the
// unrolled MP kernels; zero entries are eliminated via `if constexpr`.
// ---------------------------------------------------------------------------
namespace cgc {

constexpr double dfact(int n){ double r=1.0; for(int i=2;i<=n;++i) r*=(double)i; return r; }

constexpr double dsqrt(double x){
  if(x<=0.0) return 0.0;
  double g = x>1.0 ? x : 1.0;
  for(int i=0;i<200;++i){ double ng = 0.5*(g + x/g); if(ng==g) break; g=ng; }
  return g;
}

constexpr double cg1(int j1,int m1,int j2,int m2,int j3,int m3){
  int adiff = j1-j2; if(adiff<0) adiff=-adiff;
  if(m1+m2!=m3 || j3<adiff || j3>j1+j2) return 0.0;
  double pre = dsqrt((double)(2*j3+1)*dfact(j1+j2-j3)*dfact(j1-j2+j3)*dfact(-j1+j2+j3)/dfact(j1+j2+j3+1));
  pre = pre*dsqrt(dfact(j3+m3)*dfact(j3-m3)*dfact(j1-m1)*dfact(j1+m1)*dfact(j2-m2)*dfact(j2+m2));
  double s=0.0;
  for(int k=0;k<=j1+j2+j3;++k){
    int d1=j1+j2-j3-k, d2=j1-m1-k, d3=j2+m2-k, d4=j3-j2+m1+k, d5=j3-j1-m2+k;
    if(d1<0||d2<0||d3<0||d4<0||d5<0) continue;
    double term = 1.0/(dfact(k)*dfact(d1)*dfact(d2)*dfact(d3)*dfact(d4)*dfact(d5));
    s += (k&1)? -term : term;
  }
  return pre*s;
}

struct Tab { float v[9][9][9]; };

constexpr Tab make(){
  Tab T{};
  int off[3]={0,1,4};
  double Ure[3][5][5]={}, Uim[3][5][5]={};
  const double s2 = dsqrt(0.5);
  for(int l=0;l<3;++l){
    for(int m=-l;m<=l;++m){
      int i=m+l;
      if(m==0){ Ure[l][i][l]=1.0; }
      else if(m>0){
        Ure[l][i][l+m] = ((m&1)? -1.0:1.0)*s2;
        Ure[l][i][l-m] = s2;
      } else {
        int am=-m;
        Uim[l][i][l+m] = s2;
        Uim[l][i][l-m] = -(((am&1)?-1.0:1.0))*s2;
      }
    }
  }
  for(int l1=0;l1<3;++l1) for(int l2=0;l2<3;++l2) for(int l3=0;l3<3;++l3){
    int lo = l1-l2; if(lo<0) lo=-lo;
    if(l3<lo || l3>l1+l2) continue;
    int d1=2*l1+1, d2=2*l2+1, d3=2*l3+1;
    double cg[5][5][5]={};
    for(int m1=-l1;m1<=l1;++m1) for(int m2=-l2;m2<=l2;++m2){
      int m3=m1+m2;
      if(m3>=-l3 && m3<=l3) cg[m1+l1][m2+l2][m3+l3] = cg1(l1,m1,l2,m2,l3,m3);
    }
    double t1re[5][5][5]={}, t1im[5][5][5]={};
    for(int a=0;a<d1;++a) for(int b=0;b<d2;++b) for(int k=0;k<d3;++k){
      double sre=0, sim=0;
      for(int c=0;c<d3;++c){
        double g=cg[a][b][c]; if(g==0.0) continue;
        sre += g*Ure[l3][k][c];
        sim -= g*Uim[l3][k][c];
      }
      t1re[a][b][k]=sre; t1im[a][b][k]=sim;
    }
    double t2re[5][5][5]={}, t2im[5][5][5]={};
    for(int a=0;a<d1;++a) for(int j=0;j<d2;++j) for(int k=0;k<d3;++k){
      double sre=0,sim=0;
      for(int b=0;b<d2;++b){
        double ur=Ure[l2][j][b], ui=Uim[l2][j][b];
        if(ur==0.0&&ui==0.0) continue;
        sre += ur*t1re[a][b][k]-ui*t1im[a][b][k];
        sim += ur*t1im[a][b][k]+ui*t1re[a][b][k];
      }
      t2re[a][j][k]=sre; t2im[a][j][k]=sim;
    }
    for(int i=0;i<d1;++i) for(int j=0;j<d2;++j) for(int k=0;k<d3;++k){
      double sre=0,sim=0;
      for(int a=0;a<d1;++a){
        double ur=Ure[l1][i][a], ui=Uim[l1][i][a];
        if(ur==0.0&&ui==0.0) continue;
        sre += ur*t2re[a][j][k]-ui*t2im[a][j][k];
        sim += ur*t2im[a][j][k]+ui*t2re[a][j][k];
      }
      T.v[off[l1]+i][off[l2]+j][off[l3]+k] = (float)(sre+sim);
    }
  }
  return T;
}

constexpr Tab T = make();

} // namespace cgc

template<int I, int N, typename F>
__device__ __forceinline__ void sfor(F&& f){
  if constexpr (I < N){
    f(std::integral_constant<int,I>{});
    sfor<I+1,N>(static_cast<F&&>(f));
  }
}

constexpr int LOFF[3] = {0,1,4};

// Path sets.  Layer-1's 15 paths split by l1 so Wreg fits in registers
// without spilling.  MINW (min waves/EU for __launch_bounds__) is the VGPR
// cap: MINW=3 -> ~170 regs, MINW=4 -> 128.  R5 post-mortem: forcing MINW=4
// on PS1a (needs ~140 live) spilled to scratch -> 1.15 GB HBM traffic and
// 2x regression.  DO NOT raise MINW above these values.
struct PS0 {   // layer 0
  static constexpr int NP=3;
  static constexpr int L[3][3]={{0,0,0},{0,1,1},{0,2,2}};
  static constexpr int ALO=0, AHI=1, OD=9, WOFF=0;
  static constexpr bool ACC=false;
  static constexpr int MINW=4;
};
struct PS1a {  // layer 1, l1 in {0,1}
  static constexpr int NP=9;
  static constexpr int L[9][3]={{0,0,0},{0,1,1},{0,2,2},
                                {1,0,1},{1,1,0},{1,1,1},{1,1,2},{1,2,1},{1,2,2}};
  static constexpr int ALO=0, AHI=4, OD=9, WOFF=0;
  static constexpr bool ACC=false;
  static constexpr int MINW=3;
};
struct PS1b {  // layer 1, l1 == 2 (W rows 9..14), accumulates into y_out
  static constexpr int NP=6;
  static constexpr int L[6][3]={{2,0,2},{2,1,1},{2,1,2},{2,2,0},{2,2,1},{2,2,2}};
  static constexpr int ALO=4, AHI=9, OD=9, WOFF=9*NBASIS*N_FEAT;
  static constexpr bool ACC=true;
  static constexpr int MINW=3;
};
struct PS2 {   // layer 2
  static constexpr int NP=3;
  static constexpr int L[3][3]={{0,0,0},{1,1,0},{2,2,0}};
  static constexpr int ALO=0, AHI=9, OD=1, WOFF=0;
  static constexpr bool ACC=false;
  static constexpr int MINW=4;
};

// ---------------------------------------------------------------------------
// CSR construction on dst (idx_i). perm[e] = CSR slot of original edge e.
// ---------------------------------------------------------------------------
__global__ void zero_kernel(int* __restrict__ a, int n){
  int i = blockIdx.x*256 + threadIdx.x;
  if(i<n) a[i]=0;
}

__global__ void count_kernel(const int* __restrict__ dst, int* __restrict__ cnt, int E){
  int e = blockIdx.x*256 + threadIdx.x;
  if(e<E) atomicAdd(&cnt[dst[e]], 1);
}

__global__ void __launch_bounds__(1024) scan_kernel(const int* __restrict__ cnt,
                                                    int* __restrict__ row_ptr,
                                                    int* __restrict__ cursor, int n){
  __shared__ int part[1024];
  const int tid = threadIdx.x;
  const int chunk = (n + 1023) >> 10;
  const int s0 = tid*chunk;
  const int s1 = (s0+chunk < n) ? s0+chunk : n;
  int s=0;
  for(int i=s0;i<s1;++i) s += cnt[i];
  part[tid]=s; __syncthreads();
  for(int off=1; off<1024; off<<=1){
    int v = 0;
    if(tid>=off) v = part[tid-off];
    __syncthreads();
    part[tid] += v;
    __syncthreads();
  }
  int run = part[tid] - s;           // exclusive prefix
  for(int i=s0;i<s1;++i){
    int cv = cnt[i];
    row_ptr[i]=run; cursor[i]=run;
    run += cv;
  }
  if(tid==1023) row_ptr[n] = part[1023];
}

__global__ void fill_kernel(const int* __restrict__ dst, const int* __restrict__ src,
                            int* __restrict__ cursor, int* __restrict__ perm,
                            int* __restrict__ srcs, int E){
  int e = blockIdx.x*256 + threadIdx.x;
  if(e<E){
    int d = dst[e];
    int pos = atomicAdd(&cursor[d], 1);
    perm[e] = pos;
    srcs[pos] = src[e];
  }
}

// ---------------------------------------------------------------------------
// Per-edge geometry, written PERMUTED into CSR order (stride 20 floats):
// rad[8] (cutoff*mask folded) + Y[9] + 3 pad.
// ---------------------------------------------------------------------------
__global__ void geom_kernel(const float* __restrict__ dr, const int* __restrict__ ii,
                            const int* __restrict__ jj, const int* __restrict__ perm,
                            float* __restrict__ radY, int E){
  int e = blockIdx.x*256 + threadIdx.x;
  if(e>=E) return;
  float dx=dr[3*e], dy=dr[3*e+1], dz=dr[3*e+2];
  float r2 = fmaf(dx,dx,fmaf(dy,dy,fmaf(dz,dz,1e-12f)));
  float r = sqrtf(r2);
  float inv = 1.f/r;
  float ux=dx*inv, uy=dy*inv, uz=dz*inv;
  float t = r*(1.f/6.f);
  t = fminf(fmaxf(t,0.f), 1.f-1e-6f);
  float cut = 0.f;
  if (r < 6.f) cut = expf(1.f - 1.f/(1.f - t*t));
  if (ii[e]==jj[e]) cut = 0.f;
  float base = 0.57735026918962576f * inv * cut;   // sqrt(2/RMAX)=sqrt(1/3)
  float* o = radY + (size_t)perm[e]*20;
  const float pir = 0.52359877559829887f * r;      // pi*r/6
  #pragma unroll
  for(int nb=1; nb<=8; ++nb) o[nb-1] = base * sinf((float)nb * pir);
  o[8]  = 0.28209479177387814f;
  o[9]  = 0.4886025119029199f*uy;
  o[10] = 0.4886025119029199f*uz;
  o[11] = 0.4886025119029199f*ux;
  o[12] = 1.0925484305920792f*ux*uy;
  o[13] = 1.0925484305920792f*uy*uz;
  o[14] = 0.31539156525252005f*(3.f*uz*uz-1.f);
  o[15] = 1.0925484305920792f*ux*uz;
  o[16] = 0.5462742152960396f*(ux*ux-uy*uy);
  o[17]=0.f; o[18]=0.f; o[19]=0.f;
}

__global__ void init_kernel(const float* __restrict__ embed, const int* __restrict__ Z,
                            float* __restrict__ xA, int nN){
  int i = blockIdx.x*256 + threadIdx.x;
  if(i >= nN*N_FEAT) return;
  int n = i>>5, f = i&31;
  xA[(size_t)n*288 + f] = embed[Z[n]*N_FEAT + f];
}

// ---------------------------------------------------------------------------
// Message passing.  Grid-stride over nodes: each block loads its path
// weights ONCE, then sequentially owns many dst nodes.  Per node: 8
// interleaved edge streams (4 waves x 2 halves), lane = feature; 1-deep
// register prefetch of radY + x[src]; 2-deep of srcs; LDS tree-reduce
// across waves; write (or += for PS1b).
// ---------------------------------------------------------------------------
#define MP_GRID 1024

template<class PS>
__global__ void __launch_bounds__(256, PS::MINW) mp_kernel(
    const int* __restrict__ row_ptr, const int* __restrict__ srcs,
    const float* __restrict__ radY, const float* __restrict__ x_in,
    const float* __restrict__ W, float* __restrict__ y_out, int nN)
{
  constexpr int NP = PS::NP;
  constexpr int ALO = PS::ALO, AHI = PS::AHI, DA = AHI-ALO;
  constexpr int OD = PS::OD;
  const int tid  = threadIdx.x;
  const int f    = tid & 31;
  const int t    = tid >> 5;        // stream 0..7
  const int wave = tid >> 6;
  const bool lo32 = (tid & 63) < 32;

  __shared__ float red[3][OD][32];

  // path weights resident in VGPRs: lane f holds W[p][q][f] — loaded once
  float Wreg[NP][NBASIS];
  sfor<0,NP>([&](auto P){
    sfor<0,NBASIS>([&](auto Q){
      Wreg[P.value][Q.value] = W[PS::WOFF + (P.value*NBASIS+Q.value)*N_FEAT + f];
    });
  });

  for (int n = blockIdx.x; n < nN; n += MP_GRID){
    float msg[OD];
    sfor<0,OD>([&](auto C){ msg[C.value]=0.f; });

    const int beg = row_ptr[n], end = row_ptr[n+1];

    int k = beg + t;
    int srcB = 0;
    float4 rA0, rA1, rA2, rA3; float yA8;
    float xsA[DA];
    if (k < end){
      const float* rp = radY + (size_t)k*20;
      rA0 = *(const float4*)(rp);
      rA1 = *(const float4*)(rp+4);
      rA2 = *(const float4*)(rp+8);
      rA3 = *(const float4*)(rp+12);
      yA8 = rp[16];
      int srcA = srcs[k];
      if (k+8 < end) srcB = srcs[k+8];
      const float* xb = x_in + (size_t)srcA*288 + ALO*N_FEAT + f;
      sfor<0,DA>([&](auto A){ xsA[A.value] = xb[A.value*N_FEAT]; });
    }

    for (; k < end; ){
      const int kn = k + 8;
      // prefetch next edge: radY + x[src] in flight across this compute
      float4 rB0, rB1, rB2, rB3; float yB8;
      float xsB[DA]; int srcC = 0;
      if (kn < end){
        const float* rp = radY + (size_t)kn*20;
        rB0 = *(const float4*)(rp);
        rB1 = *(const float4*)(rp+4);
        rB2 = *(const float4*)(rp+8);
        rB3 = *(const float4*)(rp+12);
        yB8 = rp[16];
        const float* xb = x_in + (size_t)srcB*288 + ALO*N_FEAT + f;
        sfor<0,DA>([&](auto A){ xsB[A.value] = xb[A.value*N_FEAT]; });
        if (kn+8 < end) srcC = srcs[kn+8];
      }

      const float rad[8] = {rA0.x,rA0.y,rA0.z,rA0.w,rA1.x,rA1.y,rA1.z,rA1.w};
      const float Yv[9]  = {rA2.x,rA2.y,rA2.z,rA2.w,rA3.x,rA3.y,rA3.z,rA3.w,yA8};

      sfor<0,NP>([&](auto P){
        constexpr int p  = P.value;
        constexpr int l1 = PS::L[p][0], l2 = PS::L[p][1], l3 = PS::L[p][2];
        constexpr int o1 = LOFF[l1], o2 = LOFF[l2], o3 = LOFF[l3];
        float w = 0.f;
        sfor<0,NBASIS>([&](auto Q){ w = fmaf(rad[Q.value], Wreg[p][Q.value], w); });
        sfor<0,2*l2+1>([&](auto B){
          constexpr int b = B.value;
          const float yw = Yv[o2+b]*w;
          sfor<0,2*l1+1>([&](auto A){
            constexpr int a = A.value;
            sfor<0,2*l3+1>([&](auto C){
              constexpr int c = C.value;
              constexpr float cgv = cgc::T.v[o1+a][o2+b][o3+c];
              if constexpr (cgv > 1e-7f || cgv < -1e-7f){
                msg[o3+c] = fmaf(cgv*xsA[o1+a-ALO], yw, msg[o3+c]);
              }
            });
          });
        });
      });

      // rotate pipeline
      rA0=rB0; rA1=rB1; rA2=rB2; rA3=rB3; yA8=yB8;
      sfor<0,DA>([&](auto A){ xsA[A.value] = xsB[A.value]; });
      srcB = srcC;
      k = kn;
    }

    // merge half-waves within each wave
    sfor<0,OD>([&](auto C){ msg[C.value] += __shfl_down(msg[C.value], 32, 64); });

    if (wave > 0 && lo32){
      sfor<0,OD>([&](auto C){ red[wave-1][C.value][f] = msg[C.value]; });
    }
    __syncthreads();
    if (wave == 0 && lo32){
      sfor<0,OD>([&](auto C){
        float v = msg[C.value] + red[0][C.value][f] + red[1][C.value][f] + red[2][C.value][f];
        if constexpr (PS::ACC)
          y_out[((size_t)n*OD + C.value)*N_FEAT + f] += v;
        else
          y_out[((size_t)n*OD + C.value)*N_FEAT + f] = v;
      });
    }
    __syncthreads();   // red safe for next node
  }
}

// ---------------------------------------------------------------------------
// Node update for iterations 0/1: x_out = eadd(x, dense2(esilu(dense1(eadd(x,msg)))))
// ---------------------------------------------------------------------------
template<int DX>
__global__ void __launch_bounds__(256) nodeA_kernel(
    const float* __restrict__ xin, const float* __restrict__ ymsg,
    const float* __restrict__ K1, const float* __restrict__ b1,
    const float* __restrict__ K2, const float* __restrict__ b2,
    float* __restrict__ xout, int nN)
{
  __shared__ float sK1[1024], sK2[1024], sb1[32], sb2[32];
  __shared__ float tb[8][9][32];
  const int tid = threadIdx.x;
  for(int i=tid;i<1024;i+=256){ sK1[i]=K1[i]; sK2[i]=K2[i]; }
  if(tid<32){ sb1[tid]=b1[tid]; sb2[tid]=b2[tid]; }
  __syncthreads();
  const int h = tid>>5, f = tid&31;
  const int n = blockIdx.x*8 + h;
  const bool valid = n < nN;
  const int nc = valid ? n : 0;
  float xi[9];
  #pragma unroll
  for(int c=0;c<9;++c){
    float t = ymsg[((size_t)nc*9+c)*32+f];
    float x = 0.f;
    if (c<DX) x = xin[((size_t)nc*9+c)*32+f];
    xi[c]=x;
    tb[h][c][f] = t + x;
  }
  __syncthreads();
  float u[9];
  #pragma unroll
  for(int c=0;c<9;++c){
    float acc = (c==0) ? sb1[f] : 0.f;
    #pragma unroll
    for(int g=0;g<32;++g) acc = fmaf(tb[h][c][g], sK1[g*32+f], acc);
    u[c]=acc;
  }
  const float gate = 1.f/(1.f+expf(-u[0]));   // silu(s)=s*gate; others *gate
  __syncthreads();
  #pragma unroll
  for(int c=0;c<9;++c) tb[h][c][f] = u[c]*gate;
  __syncthreads();
  #pragma unroll
  for(int c=0;c<9;++c){
    float acc = (c==0) ? sb2[f] : 0.f;
    #pragma unroll
    for(int g=0;g<32;++g) acc = fmaf(tb[h][c][g], sK2[g*32+f], acc);
    if (valid) xout[((size_t)n*9+c)*32+f] = acc + ((c<DX) ? xi[c] : 0.f);
  }
}

// Final iteration node update: scalar channel only; writes d_out (nN,32)
__global__ void __launch_bounds__(256) nodeB_kernel(
    const float* __restrict__ xin, const float* __restrict__ msg0,
    const float* __restrict__ K1, const float* __restrict__ b1,
    const float* __restrict__ K2, const float* __restrict__ b2,
    float* __restrict__ out, int nN)
{
  __shared__ float sK1[1024], sK2[1024], sb1[32], sb2[32];
  __shared__ float tb[8][32];
  const int tid = threadIdx.x;
  for(int i=tid;i<1024;i+=256){ sK1[i]=K1[i]; sK2[i]=K2[i]; }
  if(tid<32){ sb1[tid]=b1[tid]; sb2[tid]=b2[tid]; }
  __syncthreads();
  const int h = tid>>5, f = tid&31;
  const int n = blockIdx.x*8 + h;
  const bool valid = n < nN;
  const int nc = valid ? n : 0;
  const float x0 = xin[(size_t)nc*288 + f];      // x[:, 0:1] scalar channel
  tb[h][f] = msg0[(size_t)nc*32+f] + x0;
  __syncthreads();
  float acc = sb1[f];
  #pragma unroll
  for(int g=0;g<32;++g) acc = fmaf(tb[h][g], sK1[g*32+f], acc);
  const float gate = 1.f/(1.f+expf(-acc));
  const float v = acc*gate;
  __syncthreads();
  tb[h][f] = v;
  __syncthreads();
  float acc2 = sb2[f];
  #pragma unroll
  for(int g=0;g<32;++g) acc2 = fmaf(tb[h][g], sK2[g*32+f], acc2);
  if (valid) out[(size_t)n*32+f] = x0 + acc2;
}

// ---------------------------------------------------------------------------
extern "C" void kernel_launch(void* const* d_in, const int* in_sizes, int n_in,
                              void* d_out, int out_size, void* d_ws, size_t ws_size,
                              hipStream_t stream) {
  const float* dr    = (const float*)d_in[0];
  const int*   Z     = (const int*)  d_in[1];
  const int*   nbr   = (const int*)  d_in[2];
  const float* embed = (const float*)d_in[3];
  const float* wmp0  = (const float*)d_in[4];
  const float* wmp1  = (const float*)d_in[5];
  const float* wmp2  = (const float*)d_in[6];
  const float* dk1   = (const float*)d_in[7];
  const float* db1   = (const float*)d_in[8];
  const float* dk2   = (const float*)d_in[9];
  const float* db2   = (const float*)d_in[10];
  const int nN = in_sizes[1];
  const int E  = in_sizes[2]/2;
  const int* idx_i = nbr;       // dst
  const int* idx_j = nbr + E;   // src

  // workspace carve-up (256B aligned)
  uintptr_t base = (uintptr_t)d_ws;
  auto alloc = [&](size_t bytes)->void*{
    uintptr_t p = (base + 255) & ~(uintptr_t)255;
    base = p + bytes;
    return (void*)p;
  };
  float* radY    = (float*)alloc((size_t)E*20*4);
  int*   cnt     = (int*)  alloc((size_t)nN*4);
  int*   cursor  = (int*)  alloc((size_t)nN*4);
  int*   row_ptr = (int*)  alloc((size_t)(nN+1)*4);
  int*   perm    = (int*)  alloc((size_t)E*4);
  int*   srcs    = (int*)  alloc((size_t)E*4);
  float* xA      = (float*)alloc((size_t)nN*288*4);
  float* xB      = (float*)alloc((size_t)nN*288*4);
  float* ymsg    = (float*)alloc((size_t)nN*288*4);

  const int gE = (E+255)/256;
  const int gN = (nN+255)/256;

  // CSR build on dst
  zero_kernel <<<gN, 256, 0, stream>>>(cnt, nN);
  count_kernel<<<gE, 256, 0, stream>>>(idx_i, cnt, E);
  scan_kernel <<<1, 1024, 0, stream>>>(cnt, row_ptr, cursor, nN);
  fill_kernel <<<gE, 256, 0, stream>>>(idx_i, idx_j, cursor, perm, srcs, E);

  // edge geometry (scattered into CSR order) + node embedding
  geom_kernel <<<gE, 256, 0, stream>>>(dr, idx_i, idx_j, perm, radY, E);
  init_kernel <<<(nN*N_FEAT+255)/256, 256, 0, stream>>>(embed, Z, xA, nN);

  const int gND = (nN+7)/8;     // 8 nodes (half-waves) per block
  const int gMP = (nN < MP_GRID) ? nN : MP_GRID;

  // iteration 0
  mp_kernel<PS0><<<gMP, 256, 0, stream>>>(row_ptr, srcs, radY, xA, wmp0, ymsg, nN);
  nodeA_kernel<1><<<gND, 256, 0, stream>>>(xA, ymsg, dk1, db1, dk2, db2, xB, nN);
  // iteration 1 (two passes: l1 in {0,1}, then l1==2 accumulating)
  mp_kernel<PS1a><<<gMP, 256, 0, stream>>>(row_ptr, srcs, radY, xB, wmp1, ymsg, nN);
  mp_kernel<PS1b><<<gMP, 256, 0, stream>>>(row_ptr, srcs, radY, xB, wmp1, ymsg, nN);
  nodeA_kernel<9><<<gND, 256, 0, stream>>>(xB, ymsg, dk1+1024, db1+32, dk2+1024, db2+32, xA, nN);
  // iteration 2 (scalar output)
  mp_kernel<PS2><<<gMP, 256, 0, stream>>>(row_ptr, srcs, radY, xA, wmp2, ymsg, nN);
  nodeB_kernel<<<gND, 256, 0, stream>>>(xA, ymsg, dk1+2048, db1+64, dk2+2048, db2+64,
                                        (float*)d_out, nN);
}

// Round 7
// 525.825 us; speedup vs baseline: 1.8401x; 1.1506x over previous
//
#include <hip/hip_runtime.h>
#include <type_traits>
#include <cstdint>
#include <cstddef>

#define N_FEAT 32
#define NBASIS 8
#define SPAN   32   // edges per half-wave slot (segmented scan granularity)

// ---------------------------------------------------------------------------
// Compile-time Clebsch-Gordan (real basis) table: constexpr port of the
// reference _cg / _u_real / _real_cg.  Values become inline literals in the
// unrolled MP kernels; zero entries are eliminated via `if constexpr`.
// ---------------------------------------------------------------------------
namespace cgc {

constexpr double dfact(int n){ double r=1.0; for(int i=2;i<=n;++i) r*=(double)i; return r; }

constexpr double dsqrt(double x){
  if(x<=0.0) return 0.0;
  double g = x>1.0 ? x : 1.0;
  for(int i=0;i<200;++i){ double ng = 0.5*(g + x/g); if(ng==g) break; g=ng; }
  return g;
}

constexpr double cg1(int j1,int m1,int j2,int m2,int j3,int m3){
  int adiff = j1-j2; if(adiff<0) adiff=-adiff;
  if(m1+m2!=m3 || j3<adiff || j3>j1+j2) return 0.0;
  double pre = dsqrt((double)(2*j3+1)*dfact(j1+j2-j3)*dfact(j1-j2+j3)*dfact(-j1+j2+j3)/dfact(j1+j2+j3+1));
  pre = pre*dsqrt(dfact(j3+m3)*dfact(j3-m3)*dfact(j1-m1)*dfact(j1+m1)*dfact(j2-m2)*dfact(j2+m2));
  double s=0.0;
  for(int k=0;k<=j1+j2+j3;++k){
    int d1=j1+j2-j3-k, d2=j1-m1-k, d3=j2+m2-k, d4=j3-j2+m1+k, d5=j3-j1-m2+k;
    if(d1<0||d2<0||d3<0||d4<0||d5<0) continue;
    double term = 1.0/(dfact(k)*dfact(d1)*dfact(d2)*dfact(d3)*dfact(d4)*dfact(d5));
    s += (k&1)? -term : term;
  }
  return pre*s;
}

struct Tab { float v[9][9][9]; };

constexpr Tab make(){
  Tab T{};
  int off[3]={0,1,4};
  double Ure[3][5][5]={}, Uim[3][5][5]={};
  const double s2 = dsqrt(0.5);
  for(int l=0;l<3;++l){
    for(int m=-l;m<=l;++m){
      int i=m+l;
      if(m==0){ Ure[l][i][l]=1.0; }
      else if(m>0){
        Ure[l][i][l+m] = ((m&1)? -1.0:1.0)*s2;
        Ure[l][i][l-m] = s2;
      } else {
        int am=-m;
        Uim[l][i][l+m] = s2;
        Uim[l][i][l-m] = -(((am&1)?-1.0:1.0))*s2;
      }
    }
  }
  for(int l1=0;l1<3;++l1) for(int l2=0;l2<3;++l2) for(int l3=0;l3<3;++l3){
    int lo = l1-l2; if(lo<0) lo=-lo;
    if(l3<lo || l3>l1+l2) continue;
    int d1=2*l1+1, d2=2*l2+1, d3=2*l3+1;
    double cg[5][5][5]={};
    for(int m1=-l1;m1<=l1;++m1) for(int m2=-l2;m2<=l2;++m2){
      int m3=m1+m2;
      if(m3>=-l3 && m3<=l3) cg[m1+l1][m2+l2][m3+l3] = cg1(l1,m1,l2,m2,l3,m3);
    }
    double t1re[5][5][5]={}, t1im[5][5][5]={};
    for(int a=0;a<d1;++a) for(int b=0;b<d2;++b) for(int k=0;k<d3;++k){
      double sre=0, sim=0;
      for(int c=0;c<d3;++c){
        double g=cg[a][b][c]; if(g==0.0) continue;
        sre += g*Ure[l3][k][c];
        sim -= g*Uim[l3][k][c];
      }
      t1re[a][b][k]=sre; t1im[a][b][k]=sim;
    }
    double t2re[5][5][5]={}, t2im[5][5][5]={};
    for(int a=0;a<d1;++a) for(int j=0;j<d2;++j) for(int k=0;k<d3;++k){
      double sre=0,sim=0;
      for(int b=0;b<d2;++b){
        double ur=Ure[l2][j][b], ui=Uim[l2][j][b];
        if(ur==0.0&&ui==0.0) continue;
        sre += ur*t1re[a][b][k]-ui*t1im[a][b][k];
        sim += ur*t1im[a][b][k]+ui*t1re[a][b][k];
      }
      t2re[a][j][k]=sre; t2im[a][j][k]=sim;
    }
    for(int i=0;i<d1;++i) for(int j=0;j<d2;++j) for(int k=0;k<d3;++k){
      double sre=0,sim=0;
      for(int a=0;a<d1;++a){
        double ur=Ure[l1][i][a], ui=Uim[l1][i][a];
        if(ur==0.0&&ui==0.0) continue;
        sre += ur*t2re[a][j][k]-ui*t2im[a][j][k];
        sim += ur*t2im[a][j][k]+ui*t2re[a][j][k];
      }
      T.v[off[l1]+i][off[l2]+j][off[l3]+k] = (float)(sre+sim);
    }
  }
  return T;
}

constexpr Tab T = make();

} // namespace cgc

template<int I, int N, typename F>
__device__ __forceinline__ void sfor(F&& f){
  if constexpr (I < N){
    f(std::integral_constant<int,I>{});
    sfor<I+1,N>(static_cast<F&&>(f));
  }
}

constexpr int LOFF[3] = {0,1,4};

// Path sets.  Layer-1's 15 paths split by l1 so Wreg fits in registers
// without spilling.  MINW caps VGPR (3 -> ~170, 4 -> 128).  R5 post-mortem:
// over-capping spills to scratch = 1.15 GB HBM traffic.  Keep PS1* at 3.
struct PS0 {   // layer 0
  static constexpr int NP=3;
  static constexpr int L[3][3]={{0,0,0},{0,1,1},{0,2,2}};
  static constexpr int ALO=0, AHI=1, OD=9, WOFF=0;
  static constexpr int MINW=4;
};
struct PS1a {  // layer 1, l1 in {0,1}
  static constexpr int NP=9;
  static constexpr int L[9][3]={{0,0,0},{0,1,1},{0,2,2},
                                {1,0,1},{1,1,0},{1,1,1},{1,1,2},{1,2,1},{1,2,2}};
  static constexpr int ALO=0, AHI=4, OD=9, WOFF=0;
  static constexpr int MINW=3;
};
struct PS1b {  // layer 1, l1 == 2 (W rows 9..14), atomically accumulates
  static constexpr int NP=6;
  static constexpr int L[6][3]={{2,0,2},{2,1,1},{2,1,2},{2,2,0},{2,2,1},{2,2,2}};
  static constexpr int ALO=4, AHI=9, OD=9, WOFF=9*NBASIS*N_FEAT;
  static constexpr int MINW=3;
};
struct PS2 {   // layer 2
  static constexpr int NP=3;
  static constexpr int L[3][3]={{0,0,0},{1,1,0},{2,2,0}};
  static constexpr int ALO=0, AHI=9, OD=1, WOFF=0;
  static constexpr int MINW=3;
};

// ---------------------------------------------------------------------------
// CSR sort on dst (idx_i). perm[e] = CSR slot of original edge e.
// ---------------------------------------------------------------------------
__global__ void zero_kernel(int* __restrict__ a, int n){
  int i = blockIdx.x*256 + threadIdx.x;
  if(i<n) a[i]=0;
}

__global__ void count_kernel(const int* __restrict__ dst, int* __restrict__ cnt, int E){
  int e = blockIdx.x*256 + threadIdx.x;
  if(e<E) atomicAdd(&cnt[dst[e]], 1);
}

__global__ void __launch_bounds__(1024) scan_kernel(const int* __restrict__ cnt,
                                                    int* __restrict__ row_ptr,
                                                    int* __restrict__ cursor, int n){
  __shared__ int part[1024];
  const int tid = threadIdx.x;
  const int chunk = (n + 1023) >> 10;
  const int s0 = tid*chunk;
  const int s1 = (s0+chunk < n) ? s0+chunk : n;
  int s=0;
  for(int i=s0;i<s1;++i) s += cnt[i];
  part[tid]=s; __syncthreads();
  for(int off=1; off<1024; off<<=1){
    int v = 0;
    if(tid>=off) v = part[tid-off];
    __syncthreads();
    part[tid] += v;
    __syncthreads();
  }
  int run = part[tid] - s;           // exclusive prefix
  for(int i=s0;i<s1;++i){
    int cv = cnt[i];
    row_ptr[i]=run; cursor[i]=run;
    run += cv;
  }
  if(tid==1023) row_ptr[n] = part[1023];
}

__global__ void fill_kernel(const int* __restrict__ dst, const int* __restrict__ src,
                            int* __restrict__ cursor, int* __restrict__ perm,
                            int* __restrict__ srcs, int* __restrict__ dsts, int E){
  int e = blockIdx.x*256 + threadIdx.x;
  if(e<E){
    int d = dst[e];
    int pos = atomicAdd(&cursor[d], 1);
    perm[e] = pos;
    srcs[pos] = src[e];
    dsts[pos] = d;
  }
}

// ---------------------------------------------------------------------------
// Per-edge geometry, written PERMUTED into CSR order (stride 20 floats):
// rad[8] (cutoff*mask folded) + Y[9] + 3 pad.
// ---------------------------------------------------------------------------
__global__ void geom_kernel(const float* __restrict__ dr, const int* __restrict__ ii,
                            const int* __restrict__ jj, const int* __restrict__ perm,
                            float* __restrict__ radY, int E){
  int e = blockIdx.x*256 + threadIdx.x;
  if(e>=E) return;
  float dx=dr[3*e], dy=dr[3*e+1], dz=dr[3*e+2];
  float r2 = fmaf(dx,dx,fmaf(dy,dy,fmaf(dz,dz,1e-12f)));
  float r = sqrtf(r2);
  float inv = 1.f/r;
  float ux=dx*inv, uy=dy*inv, uz=dz*inv;
  float t = r*(1.f/6.f);
  t = fminf(fmaxf(t,0.f), 1.f-1e-6f);
  float cut = 0.f;
  if (r < 6.f) cut = expf(1.f - 1.f/(1.f - t*t));
  if (ii[e]==jj[e]) cut = 0.f;
  float base = 0.57735026918962576f * inv * cut;   // sqrt(2/RMAX)=sqrt(1/3)
  float* o = radY + (size_t)perm[e]*20;
  const float pir = 0.52359877559829887f * r;      // pi*r/6
  #pragma unroll
  for(int nb=1; nb<=8; ++nb) o[nb-1] = base * sinf((float)nb * pir);
  o[8]  = 0.28209479177387814f;
  o[9]  = 0.4886025119029199f*uy;
  o[10] = 0.4886025119029199f*uz;
  o[11] = 0.4886025119029199f*ux;
  o[12] = 1.0925484305920792f*ux*uy;
  o[13] = 1.0925484305920792f*uy*uz;
  o[14] = 0.31539156525252005f*(3.f*uz*uz-1.f);
  o[15] = 1.0925484305920792f*ux*uz;
  o[16] = 0.5462742152960396f*(ux*ux-uy*uy);
  o[17]=0.f; o[18]=0.f; o[19]=0.f;
}

__global__ void init_kernel(const float* __restrict__ embed, const int* __restrict__ Z,
                            float* __restrict__ xA, int nN){
  int i = blockIdx.x*256 + threadIdx.x;
  if(i >= nN*N_FEAT) return;
  int n = i>>5, f = i&31;
  xA[(size_t)n*288 + f] = embed[Z[n]*N_FEAT + f];
}

// ---------------------------------------------------------------------------
// Message passing: SEGMENTED SCAN over the dst-sorted edge list.
// Each half-wave slot (lane = feature) owns SPAN contiguous edges in CSR
// order, accumulates msg in registers while dst is unchanged, and flushes
// with atomicAdd at segment boundaries (~2 flushes/span at avg degree 32).
// No __syncthreads, no LDS, uniform work per slot; radY/srcs/dsts reads
// are contiguous streams, x[src] gather is register-prefetched 1-deep.
// ymsg must be pre-zeroed (hipMemsetAsync in the launcher).
// ---------------------------------------------------------------------------
template<class PS>
__global__ void __launch_bounds__(256, PS::MINW) mp_kernel(
    const int* __restrict__ dsts, const int* __restrict__ srcs,
    const float* __restrict__ radY, const float* __restrict__ x_in,
    const float* __restrict__ W, float* __restrict__ ymsg, int E)
{
  constexpr int NP = PS::NP;
  constexpr int ALO = PS::ALO, AHI = PS::AHI, DA = AHI-ALO;
  constexpr int OD = PS::OD;
  const int tid  = threadIdx.x;
  const int f    = tid & 31;
  const int slot = blockIdx.x*8 + (tid>>5);

  int k = slot*SPAN;
  const int k1 = (k+SPAN < E) ? k+SPAN : E;
  if (k >= E) return;

  // path weights resident in VGPRs: lane f holds W[p][q][f]
  float Wreg[NP][NBASIS];
  sfor<0,NP>([&](auto P){
    sfor<0,NBASIS>([&](auto Q){
      Wreg[P.value][Q.value] = W[PS::WOFF + (P.value*NBASIS+Q.value)*N_FEAT + f];
    });
  });

  float msg[OD];
  sfor<0,OD>([&](auto C){ msg[C.value]=0.f; });

  int d = dsts[k];
  float4 rA0, rA1, rA2, rA3; float yA8;
  float xsA[DA];
  {
    const float* rp = radY + (size_t)k*20;
    rA0 = *(const float4*)(rp);
    rA1 = *(const float4*)(rp+4);
    rA2 = *(const float4*)(rp+8);
    rA3 = *(const float4*)(rp+12);
    yA8 = rp[16];
    const float* xb = x_in + (size_t)srcs[k]*288 + ALO*N_FEAT + f;
    sfor<0,DA>([&](auto A){ xsA[A.value] = xb[A.value*N_FEAT]; });
  }

  for (;;){
    const int kn = k + 1;
    const bool more = kn < k1;
    // prefetch next edge (contiguous radY/srcs/dsts; gathered x[src])
    float4 rB0, rB1, rB2, rB3; float yB8;
    float xsB[DA]; int dn = -1;
    if (more){
      const float* rp = radY + (size_t)kn*20;
      rB0 = *(const float4*)(rp);
      rB1 = *(const float4*)(rp+4);
      rB2 = *(const float4*)(rp+8);
      rB3 = *(const float4*)(rp+12);
      yB8 = rp[16];
      const float* xb = x_in + (size_t)srcs[kn]*288 + ALO*N_FEAT + f;
      sfor<0,DA>([&](auto A){ xsB[A.value] = xb[A.value*N_FEAT]; });
      dn = dsts[kn];
    }

    const float rad[8] = {rA0.x,rA0.y,rA0.z,rA0.w,rA1.x,rA1.y,rA1.z,rA1.w};
    const float Yv[9]  = {rA2.x,rA2.y,rA2.z,rA2.w,rA3.x,rA3.y,rA3.z,rA3.w,yA8};

    sfor<0,NP>([&](auto P){
      constexpr int p  = P.value;
      constexpr int l1 = PS::L[p][0], l2 = PS::L[p][1], l3 = PS::L[p][2];
      constexpr int o1 = LOFF[l1], o2 = LOFF[l2], o3 = LOFF[l3];
      float w = 0.f;
      sfor<0,NBASIS>([&](auto Q){ w = fmaf(rad[Q.value], Wreg[p][Q.value], w); });
      sfor<0,2*l2+1>([&](auto B){
        constexpr int b = B.value;
        const float yw = Yv[o2+b]*w;
        sfor<0,2*l1+1>([&](auto A){
          constexpr int a = A.value;
          sfor<0,2*l3+1>([&](auto C){
            constexpr int c = C.value;
            constexpr float cgv = cgc::T.v[o1+a][o2+b][o3+c];
            if constexpr (cgv > 1e-7f || cgv < -1e-7f){
              msg[o3+c] = fmaf(cgv*xsA[o1+a-ALO], yw, msg[o3+c]);
            }
          });
        });
      });
    });

    if (dn != d){   // segment boundary (or end of span): flush accumulator
      float* yb = ymsg + ((size_t)d*OD)*N_FEAT + f;
      sfor<0,OD>([&](auto C){
        atomicAdd(yb + C.value*N_FEAT, msg[C.value]);
        msg[C.value] = 0.f;
      });
      d = dn;
    }
    if (!more) break;

    rA0=rB0; rA1=rB1; rA2=rB2; rA3=rB3; yA8=yB8;
    sfor<0,DA>([&](auto A){ xsA[A.value] = xsB[A.value]; });
    k = kn;
  }
}

// ---------------------------------------------------------------------------
// Node update for iterations 0/1: x_out = eadd(x, dense2(esilu(dense1(eadd(x,msg)))))
// ---------------------------------------------------------------------------
template<int DX>
__global__ void __launch_bounds__(256) nodeA_kernel(
    const float* __restrict__ xin, const float* __restrict__ ymsg,
    const float* __restrict__ K1, const float* __restrict__ b1,
    const float* __restrict__ K2, const float* __restrict__ b2,
    float* __restrict__ xout, int nN)
{
  __shared__ float sK1[1024], sK2[1024], sb1[32], sb2[32];
  __shared__ float tb[8][9][32];
  const int tid = threadIdx.x;
  for(int i=tid;i<1024;i+=256){ sK1[i]=K1[i]; sK2[i]=K2[i]; }
  if(tid<32){ sb1[tid]=b1[tid]; sb2[tid]=b2[tid]; }
  __syncthreads();
  const int h = tid>>5, f = tid&31;
  const int n = blockIdx.x*8 + h;
  const bool valid = n < nN;
  const int nc = valid ? n : 0;
  float xi[9];
  #pragma unroll
  for(int c=0;c<9;++c){
    float t = ymsg[((size_t)nc*9+c)*32+f];
    float x = 0.f;
    if (c<DX) x = xin[((size_t)nc*9+c)*32+f];
    xi[c]=x;
    tb[h][c][f] = t + x;
  }
  __syncthreads();
  float u[9];
  #pragma unroll
  for(int c=0;c<9;++c){
    float acc = (c==0) ? sb1[f] : 0.f;
    #pragma unroll
    for(int g=0;g<32;++g) acc = fmaf(tb[h][c][g], sK1[g*32+f], acc);
    u[c]=acc;
  }
  const float gate = 1.f/(1.f+expf(-u[0]));   // silu(s)=s*gate; others *gate
  __syncthreads();
  #pragma unroll
  for(int c=0;c<9;++c) tb[h][c][f] = u[c]*gate;
  __syncthreads();
  #pragma unroll
  for(int c=0;c<9;++c){
    float acc = (c==0) ? sb2[f] : 0.f;
    #pragma unroll
    for(int g=0;g<32;++g) acc = fmaf(tb[h][c][g], sK2[g*32+f], acc);
    if (valid) xout[((size_t)n*9+c)*32+f] = acc + ((c<DX) ? xi[c] : 0.f);
  }
}

// Final iteration node update: scalar channel only; writes d_out (nN,32)
__global__ void __launch_bounds__(256) nodeB_kernel(
    const float* __restrict__ xin, const float* __restrict__ msg0,
    const float* __restrict__ K1, const float* __restrict__ b1,
    const float* __restrict__ K2, const float* __restrict__ b2,
    float* __restrict__ out, int nN)
{
  __shared__ float sK1[1024], sK2[1024], sb1[32], sb2[32];
  __shared__ float tb[8][32];
  const int tid = threadIdx.x;
  for(int i=tid;i<1024;i+=256){ sK1[i]=K1[i]; sK2[i]=K2[i]; }
  if(tid<32){ sb1[tid]=b1[tid]; sb2[tid]=b2[tid]; }
  __syncthreads();
  const int h = tid>>5, f = tid&31;
  const int n = blockIdx.x*8 + h;
  const bool valid = n < nN;
  const int nc = valid ? n : 0;
  const float x0 = xin[(size_t)nc*288 + f];      // x[:, 0:1] scalar channel
  tb[h][f] = msg0[(size_t)nc*32+f] + x0;
  __syncthreads();
  float acc = sb1[f];
  #pragma unroll
  for(int g=0;g<32;++g) acc = fmaf(tb[h][g], sK1[g*32+f], acc);
  const float gate = 1.f/(1.f+expf(-acc));
  const float v = acc*gate;
  __syncthreads();
  tb[h][f] = v;
  __syncthreads();
  float acc2 = sb2[f];
  #pragma unroll
  for(int g=0;g<32;++g) acc2 = fmaf(tb[h][g], sK2[g*32+f], acc2);
  if (valid) out[(size_t)n*32+f] = x0 + acc2;
}

// ---------------------------------------------------------------------------
extern "C" void kernel_launch(void* const* d_in, const int* in_sizes, int n_in,
                              void* d_out, int out_size, void* d_ws, size_t ws_size,
                              hipStream_t stream) {
  const float* dr    = (const float*)d_in[0];
  const int*   Z     = (const int*)  d_in[1];
  const int*   nbr   = (const int*)  d_in[2];
  const float* embed = (const float*)d_in[3];
  const float* wmp0  = (const float*)d_in[4];
  const float* wmp1  = (const float*)d_in[5];
  const float* wmp2  = (const float*)d_in[6];
  const float* dk1   = (const float*)d_in[7];
  const float* db1   = (const float*)d_in[8];
  const float* dk2   = (const float*)d_in[9];
  const float* db2   = (const float*)d_in[10];
  const int nN = in_sizes[1];
  const int E  = in_sizes[2]/2;
  const int* idx_i = nbr;       // dst
  const int* idx_j = nbr + E;   // src

  // workspace carve-up (256B aligned)
  uintptr_t base = (uintptr_t)d_ws;
  auto alloc = [&](size_t bytes)->void*{
    uintptr_t p = (base + 255) & ~(uintptr_t)255;
    base = p + bytes;
    return (void*)p;
  };
  float* radY    = (float*)alloc((size_t)E*20*4);
  int*   cnt     = (int*)  alloc((size_t)nN*4);
  int*   cursor  = (int*)  alloc((size_t)nN*4);
  int*   row_ptr = (int*)  alloc((size_t)(nN+1)*4);
  int*   perm    = (int*)  alloc((size_t)E*4);
  int*   srcs    = (int*)  alloc((size_t)E*4);
  int*   dsts    = (int*)  alloc((size_t)E*4);
  float* xA      = (float*)alloc((size_t)nN*288*4);
  float* xB      = (float*)alloc((size_t)nN*288*4);
  float* ymsg    = (float*)alloc((size_t)nN*288*4);

  const int gE = (E+255)/256;
  const int gN = (nN+255)/256;

  // CSR sort on dst
  zero_kernel <<<gN, 256, 0, stream>>>(cnt, nN);
  count_kernel<<<gE, 256, 0, stream>>>(idx_i, cnt, E);
  scan_kernel <<<1, 1024, 0, stream>>>(cnt, row_ptr, cursor, nN);
  fill_kernel <<<gE, 256, 0, stream>>>(idx_i, idx_j, cursor, perm, srcs, dsts, E);

  // edge geometry (scattered into CSR order) + node embedding
  geom_kernel <<<gE, 256, 0, stream>>>(dr, idx_i, idx_j, perm, radY, E);
  init_kernel <<<(nN*N_FEAT+255)/256, 256, 0, stream>>>(embed, Z, xA, nN);

  const int gND = (nN+7)/8;                       // 8 nodes (half-waves) per block
  const int nSlot = (E + SPAN - 1) / SPAN;
  const int gMP = (nSlot + 7) / 8;                // 8 slots per 256-thread block
  const size_t ymsgBytes = (size_t)nN*288*4;

  // iteration 0
  hipMemsetAsync(ymsg, 0, ymsgBytes, stream);
  mp_kernel<PS0><<<gMP, 256, 0, stream>>>(dsts, srcs, radY, xA, wmp0, ymsg, E);
  nodeA_kernel<1><<<gND, 256, 0, stream>>>(xA, ymsg, dk1, db1, dk2, db2, xB, nN);
  // iteration 1 (two passes both atomically accumulate into zeroed ymsg)
  hipMemsetAsync(ymsg, 0, ymsgBytes, stream);
  mp_kernel<PS1a><<<gMP, 256, 0, stream>>>(dsts, srcs, radY, xB, wmp1, ymsg, E);
  mp_kernel<PS1b><<<gMP, 256, 0, stream>>>(dsts, srcs, radY, xB, wmp1, ymsg, E);
  nodeA_kernel<9><<<gND, 256, 0, stream>>>(xB, ymsg, dk1+1024, db1+32, dk2+1024, db2+32, xA, nN);
  // iteration 2 (scalar output; OD=1 so only nN*32 floats used)
  hipMemsetAsync(ymsg, 0, (size_t)nN*32*4, stream);
  mp_kernel<PS2><<<gMP, 256, 0, stream>>>(dsts, srcs, radY, xA, wmp2, ymsg, E);
  nodeB_kernel<<<gND, 256, 0, stream>>>(xA, ymsg, dk1+2048, db1+64, dk2+2048, db2+64,
                                        (float*)d_out, nN);
}

// Round 8
// 434.249 us; speedup vs baseline: 2.2281x; 1.2109x over previous
//
#include <hip/hip_runtime.h>
#include <type_traits>
#include <cstdint>
#include <cstddef>

#define N_FEAT 32
#define NBASIS 8
#define SPAN   16            // edges per half-wave slot
#define BSLOTS 8             // slots per 256-thread block
#define BEDGES (SPAN*BSLOTS) // contiguous edges staged per block

// ---------------------------------------------------------------------------
// Compile-time Clebsch-Gordan (real basis) table: constexpr port of the
// reference _cg / _u_real / _real_cg.  Values become inline literals in the
// unrolled MP kernels; zero entries are eliminated via `if constexpr`.
// ---------------------------------------------------------------------------
namespace cgc {

constexpr double dfact(int n){ double r=1.0; for(int i=2;i<=n;++i) r*=(double)i; return r; }

constexpr double dsqrt(double x){
  if(x<=0.0) return 0.0;
  double g = x>1.0 ? x : 1.0;
  for(int i=0;i<200;++i){ double ng = 0.5*(g + x/g); if(ng==g) break; g=ng; }
  return g;
}

constexpr double cg1(int j1,int m1,int j2,int m2,int j3,int m3){
  int adiff = j1-j2; if(adiff<0) adiff=-adiff;
  if(m1+m2!=m3 || j3<adiff || j3>j1+j2) return 0.0;
  double pre = dsqrt((double)(2*j3+1)*dfact(j1+j2-j3)*dfact(j1-j2+j3)*dfact(-j1+j2+j3)/dfact(j1+j2+j3+1));
  pre = pre*dsqrt(dfact(j3+m3)*dfact(j3-m3)*dfact(j1-m1)*dfact(j1+m1)*dfact(j2-m2)*dfact(j2+m2));
  double s=0.0;
  for(int k=0;k<=j1+j2+j3;++k){
    int d1=j1+j2-j3-k, d2=j1-m1-k, d3=j2+m2-k, d4=j3-j2+m1+k, d5=j3-j1-m2+k;
    if(d1<0||d2<0||d3<0||d4<0||d5<0) continue;
    double term = 1.0/(dfact(k)*dfact(d1)*dfact(d2)*dfact(d3)*dfact(d4)*dfact(d5));
    s += (k&1)? -term : term;
  }
  return pre*s;
}

struct Tab { float v[9][9][9]; };

constexpr Tab make(){
  Tab T{};
  int off[3]={0,1,4};
  double Ure[3][5][5]={}, Uim[3][5][5]={};
  const double s2 = dsqrt(0.5);
  for(int l=0;l<3;++l){
    for(int m=-l;m<=l;++m){
      int i=m+l;
      if(m==0){ Ure[l][i][l]=1.0; }
      else if(m>0){
        Ure[l][i][l+m] = ((m&1)? -1.0:1.0)*s2;
        Ure[l][i][l-m] = s2;
      } else {
        int am=-m;
        Uim[l][i][l+m] = s2;
        Uim[l][i][l-m] = -(((am&1)?-1.0:1.0))*s2;
      }
    }
  }
  for(int l1=0;l1<3;++l1) for(int l2=0;l2<3;++l2) for(int l3=0;l3<3;++l3){
    int lo = l1-l2; if(lo<0) lo=-lo;
    if(l3<lo || l3>l1+l2) continue;
    int d1=2*l1+1, d2=2*l2+1, d3=2*l3+1;
    double cg[5][5][5]={};
    for(int m1=-l1;m1<=l1;++m1) for(int m2=-l2;m2<=l2;++m2){
      int m3=m1+m2;
      if(m3>=-l3 && m3<=l3) cg[m1+l1][m2+l2][m3+l3] = cg1(l1,m1,l2,m2,l3,m3);
    }
    double t1re[5][5][5]={}, t1im[5][5][5]={};
    for(int a=0;a<d1;++a) for(int b=0;b<d2;++b) for(int k=0;k<d3;++k){
      double sre=0, sim=0;
      for(int c=0;c<d3;++c){
        double g=cg[a][b][c]; if(g==0.0) continue;
        sre += g*Ure[l3][k][c];
        sim -= g*Uim[l3][k][c];
      }
      t1re[a][b][k]=sre; t1im[a][b][k]=sim;
    }
    double t2re[5][5][5]={}, t2im[5][5][5]={};
    for(int a=0;a<d1;++a) for(int j=0;j<d2;++j) for(int k=0;k<d3;++k){
      double sre=0,sim=0;
      for(int b=0;b<d2;++b){
        double ur=Ure[l2][j][b], ui=Uim[l2][j][b];
        if(ur==0.0&&ui==0.0) continue;
        sre += ur*t1re[a][b][k]-ui*t1im[a][b][k];
        sim += ur*t1im[a][b][k]+ui*t1re[a][b][k];
      }
      t2re[a][j][k]=sre; t2im[a][j][k]=sim;
    }
    for(int i=0;i<d1;++i) for(int j=0;j<d2;++j) for(int k=0;k<d3;++k){
      double sre=0,sim=0;
      for(int a=0;a<d1;++a){
        double ur=Ure[l1][i][a], ui=Uim[l1][i][a];
        if(ur==0.0&&ui==0.0) continue;
        sre += ur*t2re[a][j][k]-ui*t2im[a][j][k];
        sim += ur*t2im[a][j][k]+ui*t2re[a][j][k];
      }
      T.v[off[l1]+i][off[l2]+j][off[l3]+k] = (float)(sre+sim);
    }
  }
  return T;
}

constexpr Tab T = make();

} // namespace cgc

template<int I, int N, typename F>
__device__ __forceinline__ void sfor(F&& f){
  if constexpr (I < N){
    f(std::integral_constant<int,I>{});
    sfor<I+1,N>(static_cast<F&&>(f));
  }
}

constexpr int LOFF[3] = {0,1,4};

// Path sets.  Layer-1's 15 paths split by l1 so Wreg fits in registers
// without spilling.  MINW caps VGPR (3 -> ~170, 4 -> 128).  R5 post-mortem:
// over-capping spills to scratch = 1.15 GB HBM traffic.  Keep PS1* at 3.
struct PS0 {   // layer 0
  static constexpr int NP=3;
  static constexpr int L[3][3]={{0,0,0},{0,1,1},{0,2,2}};
  static constexpr int ALO=0, AHI=1, OD=9, WOFF=0;
  static constexpr int MINW=4;
};
struct PS1a {  // layer 1, l1 in {0,1}
  static constexpr int NP=9;
  static constexpr int L[9][3]={{0,0,0},{0,1,1},{0,2,2},
                                {1,0,1},{1,1,0},{1,1,1},{1,1,2},{1,2,1},{1,2,2}};
  static constexpr int ALO=0, AHI=4, OD=9, WOFF=0;
  static constexpr int MINW=3;
};
struct PS1b {  // layer 1, l1 == 2 (W rows 9..14), atomically accumulates
  static constexpr int NP=6;
  static constexpr int L[6][3]={{2,0,2},{2,1,1},{2,1,2},{2,2,0},{2,2,1},{2,2,2}};
  static constexpr int ALO=4, AHI=9, OD=9, WOFF=9*NBASIS*N_FEAT;
  static constexpr int MINW=3;
};
struct PS2 {   // layer 2
  static constexpr int NP=3;
  static constexpr int L[3][3]={{0,0,0},{1,1,0},{2,2,0}};
  static constexpr int ALO=0, AHI=9, OD=1, WOFF=0;
  static constexpr int MINW=3;
};

// ---------------------------------------------------------------------------
// CSR sort on dst (idx_i). perm[e] = CSR slot of original edge e.
// ---------------------------------------------------------------------------
__global__ void zero_kernel(int* __restrict__ a, int n){
  int i = blockIdx.x*256 + threadIdx.x;
  if(i<n) a[i]=0;
}

__global__ void count_kernel(const int* __restrict__ dst, int* __restrict__ cnt, int E){
  int e = blockIdx.x*256 + threadIdx.x;
  if(e<E) atomicAdd(&cnt[dst[e]], 1);
}

__global__ void __launch_bounds__(1024) scan_kernel(const int* __restrict__ cnt,
                                                    int* __restrict__ row_ptr,
                                                    int* __restrict__ cursor, int n){
  __shared__ int part[1024];
  const int tid = threadIdx.x;
  const int chunk = (n + 1023) >> 10;
  const int s0 = tid*chunk;
  const int s1 = (s0+chunk < n) ? s0+chunk : n;
  int s=0;
  for(int i=s0;i<s1;++i) s += cnt[i];
  part[tid]=s; __syncthreads();
  for(int off=1; off<1024; off<<=1){
    int v = 0;
    if(tid>=off) v = part[tid-off];
    __syncthreads();
    part[tid] += v;
    __syncthreads();
  }
  int run = part[tid] - s;           // exclusive prefix
  for(int i=s0;i<s1;++i){
    int cv = cnt[i];
    row_ptr[i]=run; cursor[i]=run;
    run += cv;
  }
  if(tid==1023) row_ptr[n] = part[1023];
}

__global__ void fill_kernel(const int* __restrict__ dst, const int* __restrict__ src,
                            int* __restrict__ cursor, int* __restrict__ perm,
                            int* __restrict__ srcs, int* __restrict__ dsts, int E){
  int e = blockIdx.x*256 + threadIdx.x;
  if(e<E){
    int d = dst[e];
    int pos = atomicAdd(&cursor[d], 1);
    perm[e] = pos;
    srcs[pos] = src[e];
    dsts[pos] = d;
  }
}

// ---------------------------------------------------------------------------
// Per-edge geometry, written PERMUTED into CSR order (stride 20 floats):
// rad[8] (cutoff*mask folded) + Y[9] + 3 pad.
// ---------------------------------------------------------------------------
__global__ void geom_kernel(const float* __restrict__ dr, const int* __restrict__ ii,
                            const int* __restrict__ jj, const int* __restrict__ perm,
                            float* __restrict__ radY, int E){
  int e = blockIdx.x*256 + threadIdx.x;
  if(e>=E) return;
  float dx=dr[3*e], dy=dr[3*e+1], dz=dr[3*e+2];
  float r2 = fmaf(dx,dx,fmaf(dy,dy,fmaf(dz,dz,1e-12f)));
  float r = sqrtf(r2);
  float inv = 1.f/r;
  float ux=dx*inv, uy=dy*inv, uz=dz*inv;
  float t = r*(1.f/6.f);
  t = fminf(fmaxf(t,0.f), 1.f-1e-6f);
  float cut = 0.f;
  if (r < 6.f) cut = expf(1.f - 1.f/(1.f - t*t));
  if (ii[e]==jj[e]) cut = 0.f;
  float base = 0.57735026918962576f * inv * cut;   // sqrt(2/RMAX)=sqrt(1/3)
  float* o = radY + (size_t)perm[e]*20;
  const float pir = 0.52359877559829887f * r;      // pi*r/6
  #pragma unroll
  for(int nb=1; nb<=8; ++nb) o[nb-1] = base * sinf((float)nb * pir);
  o[8]  = 0.28209479177387814f;
  o[9]  = 0.4886025119029199f*uy;
  o[10] = 0.4886025119029199f*uz;
  o[11] = 0.4886025119029199f*ux;
  o[12] = 1.0925484305920792f*ux*uy;
  o[13] = 1.0925484305920792f*uy*uz;
  o[14] = 0.31539156525252005f*(3.f*uz*uz-1.f);
  o[15] = 1.0925484305920792f*ux*uz;
  o[16] = 0.5462742152960396f*(ux*ux-uy*uy);
  o[17]=0.f; o[18]=0.f; o[19]=0.f;
}

__global__ void init_kernel(const float* __restrict__ embed, const int* __restrict__ Z,
                            float* __restrict__ xA, int nN){
  int i = blockIdx.x*256 + threadIdx.x;
  if(i >= nN*N_FEAT) return;
  int n = i>>5, f = i&31;
  xA[(size_t)n*288 + f] = embed[Z[n]*N_FEAT + f];
}

// ---------------------------------------------------------------------------
// Message passing: segmented scan over the dst-sorted edge list, with the
// block's ENTIRE contiguous edge range (BEDGES edges: radY + srcs + dsts)
// cooperatively staged into LDS up front (R7 post-mortem: the in-loop radY
// stream is a compulsory HBM miss ~900 cyc that 1-deep register prefetch
// can't cover; staging pays it once per block with 256 loads in flight).
// One __syncthreads total.  In-loop: LDS reads (lgkmcnt) + the x[src]
// gather (1-deep register prefetch, L2/LLC-resident).  Flush msg via
// atomicAdd at segment boundaries.  ymsg pre-zeroed by hipMemsetAsync.
// ---------------------------------------------------------------------------
template<class PS>
__global__ void __launch_bounds__(256, PS::MINW) mp_kernel(
    const int* __restrict__ dsts, const int* __restrict__ srcs,
    const float* __restrict__ radY, const float* __restrict__ x_in,
    const float* __restrict__ W, float* __restrict__ ymsg, int E)
{
  constexpr int NP = PS::NP;
  constexpr int ALO = PS::ALO, AHI = PS::AHI, DA = AHI-ALO;
  constexpr int OD = PS::OD;

  __shared__ float sRad[BEDGES*20];
  __shared__ int   sSrc[BEDGES];
  __shared__ int   sDst[BEDGES];

  const int tid  = threadIdx.x;
  const int base = blockIdx.x * BEDGES;
  const int nE   = (base + BEDGES <= E) ? BEDGES : (E - base);

  // cooperative stage: one contiguous burst, all loads in flight at once
  {
    const float4* g4 = (const float4*)(radY + (size_t)base*20);
    float4* s4 = (float4*)sRad;
    const int n4 = nE*5;                    // nE*20/4
    for (int i=tid; i<n4; i+=256) s4[i] = g4[i];
    for (int i=tid; i<nE;  i+=256){ sSrc[i]=srcs[base+i]; sDst[i]=dsts[base+i]; }
  }
  __syncthreads();

  const int f  = tid & 31;
  int k        = (tid>>5)*SPAN;             // local edge index for this slot
  const int k1 = (k+SPAN < nE) ? k+SPAN : nE;
  if (k >= nE) return;

  // path weights resident in VGPRs: lane f holds W[p][q][f]
  float Wreg[NP][NBASIS];
  sfor<0,NP>([&](auto P){
    sfor<0,NBASIS>([&](auto Q){
      Wreg[P.value][Q.value] = W[PS::WOFF + (P.value*NBASIS+Q.value)*N_FEAT + f];
    });
  });

  float msg[OD];
  sfor<0,OD>([&](auto C){ msg[C.value]=0.f; });

  int d = sDst[k];
  float xsA[DA];
  {
    const float* xb = x_in + (size_t)sSrc[k]*288 + ALO*N_FEAT + f;
    sfor<0,DA>([&](auto A){ xsA[A.value] = xb[A.value*N_FEAT]; });
  }

  for (;;){
    const int kn = k + 1;
    const bool more = kn < k1;
    // prefetch next edge's x gather (the only in-loop vmcnt chain)
    float xsB[DA]; int dn = -1;
    if (more){
      const float* xb = x_in + (size_t)sSrc[kn]*288 + ALO*N_FEAT + f;
      sfor<0,DA>([&](auto A){ xsB[A.value] = xb[A.value*N_FEAT]; });
      dn = sDst[kn];
    }

    // current edge's rad/Y from LDS (ds_read_b128, no vmcnt involvement)
    const float* rp = sRad + k*20;
    const float4 q0 = *(const float4*)(rp);
    const float4 q1 = *(const float4*)(rp+4);
    const float4 q2 = *(const float4*)(rp+8);
    const float4 q3 = *(const float4*)(rp+12);
    const float y8 = rp[16];
    const float rad[8] = {q0.x,q0.y,q0.z,q0.w,q1.x,q1.y,q1.z,q1.w};
    const float Yv[9]  = {q2.x,q2.y,q2.z,q2.w,q3.x,q3.y,q3.z,q3.w,y8};

    sfor<0,NP>([&](auto P){
      constexpr int p  = P.value;
      constexpr int l1 = PS::L[p][0], l2 = PS::L[p][1], l3 = PS::L[p][2];
      constexpr int o1 = LOFF[l1], o2 = LOFF[l2], o3 = LOFF[l3];
      float w = 0.f;
      sfor<0,NBASIS>([&](auto Q){ w = fmaf(rad[Q.value], Wreg[p][Q.value], w); });
      sfor<0,2*l2+1>([&](auto B){
        constexpr int b = B.value;
        const float yw = Yv[o2+b]*w;
        sfor<0,2*l1+1>([&](auto A){
          constexpr int a = A.value;
          sfor<0,2*l3+1>([&](auto C){
            constexpr int c = C.value;
            constexpr float cgv = cgc::T.v[o1+a][o2+b][o3+c];
            if constexpr (cgv > 1e-7f || cgv < -1e-7f){
              msg[o3+c] = fmaf(cgv*xsA[o1+a-ALO], yw, msg[o3+c]);
            }
          });
        });
      });
    });

    if (dn != d){   // segment boundary (or span end): flush accumulator
      float* yb = ymsg + ((size_t)d*OD)*N_FEAT + f;
      sfor<0,OD>([&](auto C){
        atomicAdd(yb + C.value*N_FEAT, msg[C.value]);
        msg[C.value] = 0.f;
      });
      d = dn;
    }
    if (!more) break;

    sfor<0,DA>([&](auto A){ xsA[A.value] = xsB[A.value]; });
    k = kn;
  }
}

// ---------------------------------------------------------------------------
// Node update for iterations 0/1: x_out = eadd(x, dense2(esilu(dense1(eadd(x,msg)))))
// ---------------------------------------------------------------------------
template<int DX>
__global__ void __launch_bounds__(256) nodeA_kernel(
    const float* __restrict__ xin, const float* __restrict__ ymsg,
    const float* __restrict__ K1, const float* __restrict__ b1,
    const float* __restrict__ K2, const float* __restrict__ b2,
    float* __restrict__ xout, int nN)
{
  __shared__ float sK1[1024], sK2[1024], sb1[32], sb2[32];
  __shared__ float tb[8][9][32];
  const int tid = threadIdx.x;
  for(int i=tid;i<1024;i+=256){ sK1[i]=K1[i]; sK2[i]=K2[i]; }
  if(tid<32){ sb1[tid]=b1[tid]; sb2[tid]=b2[tid]; }
  __syncthreads();
  const int h = tid>>5, f = tid&31;
  const int n = blockIdx.x*8 + h;
  const bool valid = n < nN;
  const int nc = valid ? n : 0;
  float xi[9];
  #pragma unroll
  for(int c=0;c<9;++c){
    float t = ymsg[((size_t)nc*9+c)*32+f];
    float x = 0.f;
    if (c<DX) x = xin[((size_t)nc*9+c)*32+f];
    xi[c]=x;
    tb[h][c][f] = t + x;
  }
  __syncthreads();
  float u[9];
  #pragma unroll
  for(int c=0;c<9;++c){
    float acc = (c==0) ? sb1[f] : 0.f;
    #pragma unroll
    for(int g=0;g<32;++g) acc = fmaf(tb[h][c][g], sK1[g*32+f], acc);
    u[c]=acc;
  }
  const float gate = 1.f/(1.f+expf(-u[0]));   // silu(s)=s*gate; others *gate
  __syncthreads();
  #pragma unroll
  for(int c=0;c<9;++c) tb[h][c][f] = u[c]*gate;
  __syncthreads();
  #pragma unroll
  for(int c=0;c<9;++c){
    float acc = (c==0) ? sb2[f] : 0.f;
    #pragma unroll
    for(int g=0;g<32;++g) acc = fmaf(tb[h][c][g], sK2[g*32+f], acc);
    if (valid) xout[((size_t)n*9+c)*32+f] = acc + ((c<DX) ? xi[c] : 0.f);
  }
}

// Final iteration node update: scalar channel only; writes d_out (nN,32)
__global__ void __launch_bounds__(256) nodeB_kernel(
    const float* __restrict__ xin, const float* __restrict__ msg0,
    const float* __restrict__ K1, const float* __restrict__ b1,
    const float* __restrict__ K2, const float* __restrict__ b2,
    float* __restrict__ out, int nN)
{
  __shared__ float sK1[1024], sK2[1024], sb1[32], sb2[32];
  __shared__ float tb[8][32];
  const int tid = threadIdx.x;
  for(int i=tid;i<1024;i+=256){ sK1[i]=K1[i]; sK2[i]=K2[i]; }
  if(tid<32){ sb1[tid]=b1[tid]; sb2[tid]=b2[tid]; }
  __syncthreads();
  const int h = tid>>5, f = tid&31;
  const int n = blockIdx.x*8 + h;
  const bool valid = n < nN;
  const int nc = valid ? n : 0;
  const float x0 = xin[(size_t)nc*288 + f];      // x[:, 0:1] scalar channel
  tb[h][f] = msg0[(size_t)nc*32+f] + x0;
  __syncthreads();
  float acc = sb1[f];
  #pragma unroll
  for(int g=0;g<32;++g) acc = fmaf(tb[h][g], sK1[g*32+f], acc);
  const float gate = 1.f/(1.f+expf(-acc));
  const float v = acc*gate;
  __syncthreads();
  tb[h][f] = v;
  __syncthreads();
  float acc2 = sb2[f];
  #pragma unroll
  for(int g=0;g<32;++g) acc2 = fmaf(tb[h][g], sK2[g*32+f], acc2);
  if (valid) out[(size_t)n*32+f] = x0 + acc2;
}

// ---------------------------------------------------------------------------
extern "C" void kernel_launch(void* const* d_in, const int* in_sizes, int n_in,
                              void* d_out, int out_size, void* d_ws, size_t ws_size,
                              hipStream_t stream) {
  const float* dr    = (const float*)d_in[0];
  const int*   Z     = (const int*)  d_in[1];
  const int*   nbr   = (const int*)  d_in[2];
  const float* embed = (const float*)d_in[3];
  const float* wmp0  = (const float*)d_in[4];
  const float* wmp1  = (const float*)d_in[5];
  const float* wmp2  = (const float*)d_in[6];
  const float* dk1   = (const float*)d_in[7];
  const float* db1   = (const float*)d_in[8];
  const float* dk2   = (const float*)d_in[9];
  const float* db2   = (const float*)d_in[10];
  const int nN = in_sizes[1];
  const int E  = in_sizes[2]/2;
  const int* idx_i = nbr;       // dst
  const int* idx_j = nbr + E;   // src

  // workspace carve-up (256B aligned)
  uintptr_t base = (uintptr_t)d_ws;
  auto alloc = [&](size_t bytes)->void*{
    uintptr_t p = (base + 255) & ~(uintptr_t)255;
    base = p + bytes;
    return (void*)p;
  };
  float* radY    = (float*)alloc((size_t)E*20*4);
  int*   cnt     = (int*)  alloc((size_t)nN*4);
  int*   cursor  = (int*)  alloc((size_t)nN*4);
  int*   row_ptr = (int*)  alloc((size_t)(nN+1)*4);
  int*   perm    = (int*)  alloc((size_t)E*4);
  int*   srcs    = (int*)  alloc((size_t)E*4);
  int*   dsts    = (int*)  alloc((size_t)E*4);
  float* xA      = (float*)alloc((size_t)nN*288*4);
  float* xB      = (float*)alloc((size_t)nN*288*4);
  float* ymsg    = (float*)alloc((size_t)nN*288*4);

  const int gE = (E+255)/256;
  const int gN = (nN+255)/256;

  // CSR sort on dst
  zero_kernel <<<gN, 256, 0, stream>>>(cnt, nN);
  count_kernel<<<gE, 256, 0, stream>>>(idx_i, cnt, E);
  scan_kernel <<<1, 1024, 0, stream>>>(cnt, row_ptr, cursor, nN);
  fill_kernel <<<gE, 256, 0, stream>>>(idx_i, idx_j, cursor, perm, srcs, dsts, E);

  // edge geometry (scattered into CSR order) + node embedding
  geom_kernel <<<gE, 256, 0, stream>>>(dr, idx_i, idx_j, perm, radY, E);
  init_kernel <<<(nN*N_FEAT+255)/256, 256, 0, stream>>>(embed, Z, xA, nN);

  const int gND = (nN+7)/8;                       // 8 nodes (half-waves) per block
  const int gMP = (E + BEDGES - 1) / BEDGES;      // blocks own BEDGES contiguous edges
  const size_t ymsgBytes = (size_t)nN*288*4;

  // iteration 0
  hipMemsetAsync(ymsg, 0, ymsgBytes, stream);
  mp_kernel<PS0><<<gMP, 256, 0, stream>>>(dsts, srcs, radY, xA, wmp0, ymsg, E);
  nodeA_kernel<1><<<gND, 256, 0, stream>>>(xA, ymsg, dk1, db1, dk2, db2, xB, nN);
  // iteration 1 (two passes both atomically accumulate into zeroed ymsg)
  hipMemsetAsync(ymsg, 0, ymsgBytes, stream);
  mp_kernel<PS1a><<<gMP, 256, 0, stream>>>(dsts, srcs, radY, xB, wmp1, ymsg, E);
  mp_kernel<PS1b><<<gMP, 256, 0, stream>>>(dsts, srcs, radY, xB, wmp1, ymsg, E);
  nodeA_kernel<9><<<gND, 256, 0, stream>>>(xB, ymsg, dk1+1024, db1+32, dk2+1024, db2+32, xA, nN);
  // iteration 2 (scalar output; OD=1 so only nN*32 floats used)
  hipMemsetAsync(ymsg, 0, (size_t)nN*32*4, stream);
  mp_kernel<PS2><<<gMP, 256, 0, stream>>>(dsts, srcs, radY, xA, wmp2, ymsg, E);
  nodeB_kernel<<<gND, 256, 0, stream>>>(xA, ymsg, dk1+2048, db1+64, dk2+2048, db2+64,
                                        (float*)d_out, nN);
}